// Round 18
// baseline (70.357 us; speedup 1.0000x reference)
//
#include <hip/hip_runtime.h>
#include <math.h>

#define BOS_TAG 62
#define EOS_TAG 63
#define S_LEN   1024
#define NCH     32
#define CH      32          // S_LEN / NCH
#define WPB     2           // NCH/16: halves per batch; one wave does fwd+bwd of a half
#define LN2F    0.69314718055994530942f

typedef short  short8 __attribute__((ext_vector_type(8)));
typedef unsigned short ushort4v __attribute__((ext_vector_type(4)));
typedef float  f32x4  __attribute__((ext_vector_type(4)));

template <int CTRL>
__device__ __forceinline__ int dpp_mov(int v) {
  return __builtin_amdgcn_update_dpp(v, v, CTRL, 0xf, 0xf, false);
}
template <int CTRL>
__device__ __forceinline__ float dpp_fmax_step(float v) {
  return fmaxf(v, __int_as_float(dpp_mov<CTRL>(__float_as_int(v))));
}
__device__ __forceinline__ float wave_fmax_all(float v) {
  v = dpp_fmax_step<0x111>(v); v = dpp_fmax_step<0x112>(v);
  v = dpp_fmax_step<0x114>(v); v = dpp_fmax_step<0x118>(v);
  v = dpp_fmax_step<0x142>(v); v = dpp_fmax_step<0x143>(v);
  return __int_as_float(__builtin_amdgcn_readlane(__float_as_int(v), 63));
}
template <int CTRL>
__device__ __forceinline__ float dpp_fadd_step(float v) {
  int t = __builtin_amdgcn_update_dpp(0, __float_as_int(v), CTRL, 0xf, 0xf, true);
  return v + __int_as_float(t);
}
__device__ __forceinline__ float wave_sum_all(float v) {
  v = dpp_fadd_step<0x111>(v); v = dpp_fadd_step<0x112>(v);
  v = dpp_fadd_step<0x114>(v); v = dpp_fadd_step<0x118>(v);
  v = dpp_fadd_step<0x142>(v); v = dpp_fadd_step<0x143>(v);
  return __int_as_float(__builtin_amdgcn_readlane(__float_as_int(v), 63));
}
__device__ __forceinline__ unsigned short f2bf(float v) {   // round-half-up (positive)
  return (unsigned short)((__float_as_uint(v) + 0x8000u) >> 16);
}
__device__ __forceinline__ float bf2f(unsigned short u) {
  return __uint_as_float(((unsigned)u) << 16);
}

// ===== lens: len[b] = round(sum(mask[b,:])) =====
__global__ __launch_bounds__(256) void crf_lens(
    const float* __restrict__ mask, int* __restrict__ lens, int B)
{
  const int b = blockIdx.x * 4 + (threadIdx.x >> 6);
  if (b >= B) return;
  const int l = threadIdx.x & 63;
  const float4* mb = (const float4*)(mask + (size_t)b * S_LEN);
  float s = 0.f;
#pragma unroll
  for (int i = 0; i < 4; ++i) { float4 q = mb[l + 64 * i]; s += q.x + q.y + q.z + q.w; }
  s = wave_sum_all(s);
  if (l == 0) lens[b] = max(1, min(S_LEN, (int)(s + 0.5f)));
}

// ===== ptab: per-lane MFMA B-fragment table + exp(trans[:,EOS]) =====
__global__ __launch_bounds__(256) void crf_ptab(
    const float* __restrict__ trans, short8* __restrict__ pfrag,
    float* __restrict__ tvf)
{
  const int tid = threadIdx.x;
  for (int e = tid; e < 1024; e += 256) {
    int lane = e & 63, n = (e >> 6) & 3, kc = (e >> 8) & 1, dir = e >> 9;
    int g = lane >> 4, c = lane & 15, col = 4 * c + n;
    short8 f;
#pragma unroll
    for (int j = 0; j < 8; ++j) {
      int k = kc * 32 + g * 8 + j;
      float tv = dir ? trans[col * 64 + k] : trans[k * 64 + col];
      f[j] = (short)f2bf(__expf(tv));
    }
    pfrag[e] = f;
  }
  if (tid < 64) tvf[tid] = __expf(trans[tid * 64 + EOS_TAG]);
}

// ===== MFMA chunk kernel: fwd+bwd of one (b,half) INTERLEAVED in one wave =====
// 1024 waves = 1/SIMD. Two independent 16-chain scans per wave (separate LDS
// buffers, sigma); each fills the other's latency shadow, and both stream the
// SAME emission region (L2 reuse). Bodies are the R10/R16-proven forms.
// fwd: V <- (V x P) .* E_t.  bwd: V <- (V .* E_t) x P^T (A-side multiply).
// fstep/ps/pr shared (depend only on half,len). Prefetch depth 2/scan.
// launch_bounds (256,1): grid is 1 block/CU by construction; loose bound
// avoids the R11 spill trap. Watch WRITE_SIZE for spill regression.
__global__ __launch_bounds__(256, 1) void crf_chunk_mfma(
    const float* __restrict__ em, const float* __restrict__ trans,
    const int* __restrict__ lens, const short8* __restrict__ pfrag,
    unsigned short* __restrict__ Vf, unsigned short* __restrict__ Vb,
    float* __restrict__ sf, float* __restrict__ sb,
    float* __restrict__ m0a, int B)
{
  __shared__ unsigned short smem[4][2][16 * 64];
  const int wv = threadIdx.x >> 6;
  const int l  = threadIdx.x & 63;
  const int w  = blockIdx.x * 4 + wv;
  const int nwaves = B * WPB;
  if (w >= nwaves) return;
  const int b    = w / WPB;
  const int half = w % WPB;
  unsigned short* smf = smem[wv][0];
  unsigned short* smb = smem[wv][1];
  const float* embase = em + (size_t)b * S_LEN * 64;
  const int g = l >> 4, c = l & 15;

  const int len = lens[b];

  // ---- alpha0 (half==0 only) ----
  float v_row0 = 1.0f;
  if (half == 0) {
    float a0 = trans[BOS_TAG * 64 + l] + embase[l];
    float m0 = wave_fmax_all(a0);
    v_row0 = __expf(a0 - m0);
    if (l == 0) m0a[b] = m0;
  }

  // ---- per-row step counts; pre-save empty rows (both dirs); partial row ----
  int fstep[16];
  int ps = -1, pr = -1;
#pragma unroll
  for (int r = 0; r < 16; ++r) {
    int kg = half * 16 + r;
    int tend = min((kg + 1) * CH, len - 1);
    fstep[r] = tend - (kg * CH + 1);
    if (fstep[r] < 0) {
      Vf[((size_t)b * NCH + kg) * 64 + l] = 0x3F80; // bf16 1.0
      Vb[((size_t)b * NCH + kg) * 64 + l] = 0x3F80;
      if (l == 0) { sf[b * NCH + kg] = 0.f; sb[b * NCH + kg] = 0.f; }
    }
    if (fstep[r] >= 0 && fstep[r] < CH - 1) { ps = fstep[r]; pr = r; }
  }

  if (half * 16 * CH + 1 > len - 1) return; // fully-empty wave

  // ---- B fragments for both dirs: 16 coalesced 16B loads ----
  short8 BfF[2][4], BfB[2][4];
#pragma unroll
  for (int kc = 0; kc < 2; ++kc)
#pragma unroll
    for (int n = 0; n < 4; ++n) {
      BfF[kc][n] = pfrag[(kc * 4 + n) * 64 + l];
      BfB[kc][n] = pfrag[512 + (kc * 4 + n) * 64 + l];
    }

  // ---- init V rows (swizzled LDS [16][64] bf16), both scans ----
#pragma unroll
  for (int r = 0; r < 16; ++r) {
    float vf0 = (half == 0 && r == 0) ? v_row0 : 1.0f;
    smf[(r * 64 + l) ^ ((r & 7) << 3)] = f2bf(vf0);
    smb[(r * 64 + l) ^ ((r & 7) << 3)] = f2bf(1.0f);
  }

  const int byteA0 = (c * 128 + g * 16) ^ ((c & 7) << 4);
  const int byteA1 = (c * 128 + 64 + g * 16) ^ ((c & 7) << 4);
  int sigF = 0, sigB = 0;

  auto renorm16 = [&](float* d, int& sig) {
    float m = d[0];
#pragma unroll
    for (int i = 1; i < 16; ++i) m = fmaxf(m, d[i]);
    m = wave_fmax_all(m);
    int e = ((__float_as_int(m) >> 23) & 0xff) - 127;
    float s = __int_as_float((127 - e) << 23);
#pragma unroll
    for (int i = 0; i < 16; ++i) d[i] *= s;
    sig += e;
  };
  auto save_row = [&](int r, const unsigned short* smw,
                      unsigned short* Vout, float* sout, int sig) {
    unsigned short v = smw[(r * 64 + l) ^ ((r & 7) << 3)];
    int kg = half * 16 + r;
    Vout[((size_t)b * NCH + kg) * 64 + l] = v;
    if (l == 0) sout[b * NCH + kg] = (float)sig;
  };
  auto write_d = [&](const float* d, unsigned short* smw) {
#pragma unroll
    for (int reg = 0; reg < 4; ++reg) {
      int row = g * 4 + reg;
      ushort4v wq;
#pragma unroll
      for (int n = 0; n < 4; ++n) wq[n] = f2bf(d[reg * 4 + n]);
      *reinterpret_cast<ushort4v*>(
          (char*)smw + ((row * 128 + c * 8) ^ ((row & 7) << 4))) = wq;
    }
  };

  // ---- fwd emission addressing (rows g*4+reg), bwd addressing (rows c) ----
  int tb0[4];
#pragma unroll
  for (int reg = 0; reg < 4; ++reg) tb0[reg] = (half * 16 + g * 4 + reg) * CH + 1;
  const int tendl = min((half * 16 + c + 1) * CH, len - 1);

  auto loadF = [&](float4* q, int tl) {
#pragma unroll
    for (int reg = 0; reg < 4; ++reg) {
      int tr = min(tb0[reg] + tl, S_LEN - 1);
      q[reg] = *reinterpret_cast<const float4*>(embase + (size_t)tr * 64 + 4 * c);
    }
  };
  auto loadB = [&](float4* q, int tl) {
    int tr = max(tendl - tl, 0);
    const float* rowp = embase + (size_t)tr * 64;
    q[0] = *reinterpret_cast<const float4*>(rowp + 8 * g);
    q[1] = *reinterpret_cast<const float4*>(rowp + 8 * g + 4);
    q[2] = *reinterpret_cast<const float4*>(rowp + 32 + 8 * g);
    q[3] = *reinterpret_cast<const float4*>(rowp + 32 + 8 * g + 4);
  };

  auto bodyF = [&](const float4* q, int tl, bool rn) {
    f32x4 acc[4];
    {
      short8 a0 = *reinterpret_cast<const short8*>((const char*)smf + byteA0);
      short8 a1 = *reinterpret_cast<const short8*>((const char*)smf + byteA1);
#pragma unroll
      for (int n = 0; n < 4; ++n) {
        f32x4 z = {0.f, 0.f, 0.f, 0.f};
        z = __builtin_amdgcn_mfma_f32_16x16x32_bf16(a0, BfF[0][n], z, 0, 0, 0);
        acc[n] = __builtin_amdgcn_mfma_f32_16x16x32_bf16(a1, BfF[1][n], z, 0, 0, 0);
      }
    }
    float d[16];
#pragma unroll
    for (int reg = 0; reg < 4; ++reg) {
      d[reg * 4 + 0] = acc[0][reg] * __expf(q[reg].x);
      d[reg * 4 + 1] = acc[1][reg] * __expf(q[reg].y);
      d[reg * 4 + 2] = acc[2][reg] * __expf(q[reg].z);
      d[reg * 4 + 3] = acc[3][reg] * __expf(q[reg].w);
    }
    if (rn) renorm16(d, sigF);
    write_d(d, smf);
    if (tl == ps) save_row(pr, smf, Vf, sf, sigF);
  };
  auto bodyB = [&](const float4* q, int tl, bool rn) {
    short8 ar0 = *reinterpret_cast<const short8*>((const char*)smb + byteA0);
    short8 ar1 = *reinterpret_cast<const short8*>((const char*)smb + byteA1);
    short8 a0, a1;
#pragma unroll
    for (int j = 0; j < 4; ++j) {
      a0[j]     = (short)f2bf(bf2f((unsigned short)ar0[j])     * __expf(((const float*)&q[0])[j]));
      a0[4 + j] = (short)f2bf(bf2f((unsigned short)ar0[4 + j]) * __expf(((const float*)&q[1])[j]));
      a1[j]     = (short)f2bf(bf2f((unsigned short)ar1[j])     * __expf(((const float*)&q[2])[j]));
      a1[4 + j] = (short)f2bf(bf2f((unsigned short)ar1[4 + j]) * __expf(((const float*)&q[3])[j]));
    }
    f32x4 acc[4];
#pragma unroll
    for (int n = 0; n < 4; ++n) {
      f32x4 z = {0.f, 0.f, 0.f, 0.f};
      z = __builtin_amdgcn_mfma_f32_16x16x32_bf16(a0, BfB[0][n], z, 0, 0, 0);
      acc[n] = __builtin_amdgcn_mfma_f32_16x16x32_bf16(a1, BfB[1][n], z, 0, 0, 0);
    }
    float d[16];
#pragma unroll
    for (int reg = 0; reg < 4; ++reg)
#pragma unroll
      for (int n = 0; n < 4; ++n) d[reg * 4 + n] = acc[n][reg];
    if (rn) renorm16(d, sigB);
    write_d(d, smb);
    if (tl == ps) save_row(pr, smb, Vb, sb, sigB);
  };

  // ---- interleaved main loop: depth-2 prefetch per scan ----
  float4 pf0[4], pf1[4], pb0[4], pb1[4];
  loadF(pf0, 0); loadB(pb0, 0); loadF(pf1, 1); loadB(pb1, 1);
#pragma unroll 1
  for (int t4 = 0; t4 < CH; t4 += 4) {
    bodyF(pf0, t4 + 0, false); loadF(pf0, t4 + 2);
    bodyB(pb0, t4 + 0, false); loadB(pb0, t4 + 2);
    bodyF(pf1, t4 + 1, false); loadF(pf1, t4 + 3);
    bodyB(pb1, t4 + 1, false); loadB(pb1, t4 + 3);
    bodyF(pf0, t4 + 2, false); loadF(pf0, t4 + 4);
    bodyB(pb0, t4 + 2, false); loadB(pb0, t4 + 4);
    bodyF(pf1, t4 + 3, true);  loadF(pf1, t4 + 5);
    bodyB(pb1, t4 + 3, true);  loadB(pb1, t4 + 5);
  }
#pragma unroll
  for (int r = 0; r < 16; ++r)
    if (fstep[r] == CH - 1) {
      save_row(r, smf, Vf, sf, sigF);
      save_row(r, smb, Vb, sb, sigB);
    }
}

// ===== combine: one wave per (b,k) term; includes gold-score slice =====
__global__ __launch_bounds__(256) void crf_combine(
    const float* __restrict__ em, const int* __restrict__ tags,
    const float* __restrict__ trans, const int* __restrict__ lens,
    const unsigned short* __restrict__ Vf, const unsigned short* __restrict__ Vb,
    const float* __restrict__ sf, const float* __restrict__ sb,
    const float* __restrict__ m0a, const float* __restrict__ tvf,
    float* __restrict__ term, int B)
{
  const int item = blockIdx.x * 4 + (threadIdx.x >> 6);
  if (item >= B * NCH) return;
  const int b = item / NCH, k = item - b * NCH;
  const int l = threadIdx.x & 63;
  const int len = lens[b];
  const int kb = (len >= 2) ? (len - 2) / CH : 0;

  const int* tb = tags + (size_t)b * S_LEN;
  const float* emb = em + (size_t)b * S_LEN * 64;

  float t = 0.f;
  // ---- gold score slice (negated): steps t0 = k*CH+1 .. min((k+1)CH, len-1)
  {
    float sc = 0.f;
    int t0 = k * CH + 1 + l;
    if (l < CH && t0 <= len - 1) {
      int cur = tb[t0], prev = tb[t0 - 1];
      sc = emb[(size_t)t0 * 64 + cur] + trans[prev * 64 + cur];
    }
    if (k == 0) {
      if (l == 32) sc += trans[BOS_TAG * 64 + tb[0]] + emb[tb[0]];
      if (l == 33) sc += trans[tb[len - 1] * 64 + EOS_TAG];
    }
    t -= wave_sum_all(sc);
  }

  const unsigned short* vf = Vf + ((size_t)b * NCH + k) * 64;
  if (k == 0) {
    float v0 = bf2f(vf[l]);
    if (kb == 0) {
      t += m0a[b] + LN2F * sf[b * NCH] + __logf(wave_sum_all(v0 * tvf[l]));
    } else {
      t += m0a[b] + LN2F * (sf[b * NCH] + sb[b * NCH + 1])
         + __logf(wave_sum_all(v0 * bf2f(Vb[((size_t)b * NCH + 1) * 64 + l])));
    }
  } else if (k < kb) {
    float vk = bf2f(vf[l]);
    t += LN2F * sb[b * NCH + k + 1]
       + __logf(wave_sum_all(vk * bf2f(Vb[((size_t)b * NCH + k + 1) * 64 + l])))
       - __logf(wave_sum_all(vk));
  } else if (k == kb) {
    float vk = bf2f(vf[l]);
    t += __logf(wave_sum_all(vk * tvf[l])) - __logf(wave_sum_all(vk));
  }

  if (l == 0) term[item] = t;
}

// ===== final: sum all terms -> out[0] =====
__global__ __launch_bounds__(1024) void crf_final(
    const float* __restrict__ term, float* __restrict__ out, int n)
{
  __shared__ float red[16];
  float s = 0.f;
  for (int i = threadIdx.x; i < n; i += 1024) s += term[i];
  s = wave_sum_all(s);
  const int wid = threadIdx.x >> 6;
  if ((threadIdx.x & 63) == 0) red[wid] = s;
  __syncthreads();
  if (threadIdx.x == 0) {
    float tot = 0.f;
#pragma unroll
    for (int i = 0; i < 16; ++i) tot += red[i];
    out[0] = tot;
  }
}

// ===== fallback: monolithic per-batch forward (VALU, linear space) =====
__global__ __launch_bounds__(64) void crf_mono(
    const float* __restrict__ em, const int* __restrict__ tags,
    const float* __restrict__ mask, const float* __restrict__ trans,
    float* __restrict__ partial)
{
  const int b = blockIdx.x;
  const int l = threadIdx.x;
  const float* emb = em + (size_t)b * S_LEN * 64;
  const float* mb = mask + (size_t)b * S_LEN;
  float lenf = 0.f;
  for (int t = l; t < S_LEN; t += 64) lenf += mb[t];
  lenf = wave_sum_all(lenf);
  const int len = max(1, min(S_LEN, (int)(lenf + 0.5f)));

  float p[64];
#pragma unroll
  for (int i = 0; i < 64; ++i) p[i] = __expf(trans[i * 64 + l]) * 0.015625f;

  const int* tb = tags + (size_t)b * S_LEN;
  float sc = 0.f;
  for (int tt = 1 + l; tt <= len - 1; tt += 64)
    sc += emb[(size_t)tt * 64 + tb[tt]] + trans[tb[tt - 1] * 64 + tb[tt]];
  sc = wave_sum_all(sc);
  sc += trans[BOS_TAG * 64 + tb[0]] + emb[tb[0]] + trans[tb[len - 1] * 64 + EOS_TAG];

  float a0 = trans[BOS_TAG * 64 + l] + emb[l];
  float m0 = wave_fmax_all(a0);
  float v = __expf(a0 - m0);
  int sigma = 0;
  for (int t = 1; t <= len - 1; ++t) {
    float E = __expf(emb[(size_t)t * 64 + l]);
    int xi = __float_as_int(v);
    float s0 = 0.f, s1 = 0.f, s2 = 0.f, s3 = 0.f;
#pragma unroll
    for (int i = 0; i < 64; i += 4) {
      s0 = fmaf(__int_as_float(__builtin_amdgcn_readlane(xi, i + 0)), p[i + 0], s0);
      s1 = fmaf(__int_as_float(__builtin_amdgcn_readlane(xi, i + 1)), p[i + 1], s1);
      s2 = fmaf(__int_as_float(__builtin_amdgcn_readlane(xi, i + 2)), p[i + 2], s2);
      s3 = fmaf(__int_as_float(__builtin_amdgcn_readlane(xi, i + 3)), p[i + 3], s3);
    }
    v = ((s0 + s1) + (s2 + s3)) * E;
    float m = wave_fmax_all(v);
    int e = ((__float_as_int(m) >> 23) & 0xff) - 127;
    sigma += e + 6;
    v *= __int_as_float((127 - e) << 23);
  }
  float tvec = __expf(trans[l * 64 + EOS_TAG]);
  float lp = m0 + LN2F * (float)sigma + __logf(wave_sum_all(v * tvec));
  if (l == 0) partial[b] = lp - sc;
}

extern "C" void kernel_launch(void* const* d_in, const int* in_sizes, int n_in,
                              void* d_out, int out_size, void* d_ws, size_t ws_size,
                              hipStream_t stream) {
  const float* em = (const float*)d_in[0];
  const int* tags = (const int*)d_in[1];
  const float* mask = (const float*)d_in[2];
  const float* trans = (const float*)d_in[3];
  float* out = (float*)d_out;

  const int B = in_sizes[1] / S_LEN;

  const size_t nSig = (size_t)B * NCH;
  const size_t nV   = (size_t)B * NCH * 64;
  const size_t need = 16384 + 64 * sizeof(float)
                    + (3 * nSig + (size_t)B) * sizeof(float)
                    + (size_t)B * sizeof(int)
                    + 2 * nV * sizeof(unsigned short);

  if (ws_size >= need) {
    short8* pfrag = (short8*)d_ws;
    float* tvf  = (float*)((char*)d_ws + 16384);
    float* sf   = tvf + 64;
    float* sb   = sf + nSig;
    float* m0a  = sb + nSig;
    float* term = m0a + B;
    int*   lens = (int*)(term + nSig);
    unsigned short* Vf = (unsigned short*)(lens + B);
    unsigned short* Vb = Vf + nV;

    crf_lens<<<(B + 3) / 4, 256, 0, stream>>>(mask, lens, B);
    crf_ptab<<<1, 256, 0, stream>>>(trans, pfrag, tvf);
    const int nwaves = B * WPB;
    crf_chunk_mfma<<<(nwaves + 3) / 4, 256, 0, stream>>>(
        em, trans, lens, pfrag, Vf, Vb, sf, sb, m0a, B);
    crf_combine<<<(B * NCH + 3) / 4, 256, 0, stream>>>(
        em, tags, trans, lens, Vf, Vb, sf, sb, m0a, tvf, term, B);
    crf_final<<<1, 1024, 0, stream>>>(term, out, B * NCH);
  } else {
    float* partial = (float*)d_ws;
    crf_mono<<<B, 64, 0, stream>>>(em, tags, mask, trans, partial);
    crf_final<<<1, 1024, 0, stream>>>(partial, out, B);
  }
}